// Round 11
// baseline (482.723 us; speedup 1.0000x reference)
//
#include <hip/hip_runtime.h>
#include <hip/hip_bf16.h>
#include <math.h>

#define DI __device__ __forceinline__

constexpr int NN   = 20000;
constexpr int NE   = 160000;
constexpr int FIN  = 64;
constexpr int HIDC = 256;
constexpr int NH   = 4;
constexpr int NOUT = 3328;   // 3*1024 (QKV) + 256 (skip)

typedef __attribute__((ext_vector_type(8))) short short8;
typedef __attribute__((ext_vector_type(4))) float f32x4;

DI float bf2f(unsigned short u) { return __uint_as_float(((unsigned)u) << 16); }

DI void gld16(const void* g, void* l) {
  __builtin_amdgcn_global_load_lds((const __attribute__((address_space(1))) unsigned*)g,
                                   (__attribute__((address_space(3))) unsigned*)l, 16, 0, 0);
}

// ---------------- merged input cast + degree count ----------------
__global__ void k_prep(const float* __restrict__ x, __hip_bfloat16* __restrict__ xb,
                       const int* __restrict__ dst, int* __restrict__ deg) {
  int gid = blockIdx.x * 256 + threadIdx.x;
  if (gid < NN * FIN) xb[gid] = __float2bfloat16(x[gid]);
  if (gid < NE) atomicAdd(&deg[dst[gid]], 1);
}

__global__ void k_scan(const int* __restrict__ deg, int* __restrict__ offs,
                       int* __restrict__ cursor, int n_) {
  __shared__ int part[1024];
  int tid = threadIdx.x;
  const int CH = (n_ + 1023) >> 10;
  int base = tid * CH;
  int s = 0;
  for (int i = 0; i < CH; ++i) { int idx = base + i; if (idx < n_) s += deg[idx]; }
  part[tid] = s;
  __syncthreads();
  for (int off = 1; off < 1024; off <<= 1) {
    int v = (tid >= off) ? part[tid - off] : 0;
    __syncthreads();
    part[tid] += v;
    __syncthreads();
  }
  int run = (tid == 0) ? 0 : part[tid - 1];
  for (int i = 0; i < CH; ++i) {
    int idx = base + i;
    if (idx < n_) { offs[idx] = run; cursor[idx] = run; run += deg[idx]; }
  }
  if (tid == 1023) offs[n_] = run;
}

__global__ void k_scatter(const int* __restrict__ dst, int* __restrict__ cursor,
                          int* __restrict__ eid, int e_) {
  int e = blockIdx.x * blockDim.x + threadIdx.x;
  if (e < e_) {
    int p = atomicAdd(&cursor[dst[e]], 1);
    eid[p] = e;
  }
}

// ------ deterministic order: insertion-sort each node's edges, then materialize sse ------
__global__ void k_sortsse(const int* __restrict__ offs, int* __restrict__ eid,
                          const int* __restrict__ src, int* __restrict__ sse, int n_) {
  int n = blockIdx.x * 256 + threadIdx.x;
  if (n >= n_) return;
  int s0 = offs[n], s1 = offs[n + 1];
  for (int i = s0 + 1; i < s1; ++i) {
    int v = eid[i];
    int j = i - 1;
    while (j >= s0 && eid[j] > v) { eid[j + 1] = eid[j]; --j; }
    eid[j + 1] = v;
  }
  for (int i = s0; i < s1; ++i) sse[i] = src[eid[i]];
}

// ---------------- weight pack: Wt[n][k] = concat(wq|wk|wv|ws)[k][n], bf16 ----------------
template <int K>
__global__ void k_pack(const float* __restrict__ wq, const float* __restrict__ bq,
                       const float* __restrict__ wk, const float* __restrict__ bk,
                       const float* __restrict__ wv, const float* __restrict__ bv,
                       const float* __restrict__ ws, const float* __restrict__ bs,
                       __hip_bfloat16* __restrict__ Wt, float* __restrict__ biasp) {
  int n = blockIdx.x * 128 + threadIdx.x;  // 0..3327
  int k = blockIdx.y;                      // 0..K-1
  const float* w; const float* b; int off; int M;
  if (n < 1024)      { w = wq; b = bq; off = n;        M = 1024; }
  else if (n < 2048) { w = wk; b = bk; off = n - 1024; M = 1024; }
  else if (n < 3072) { w = wv; b = bv; off = n - 2048; M = 1024; }
  else               { w = ws; b = bs; off = n - 3072; M = 256;  }
  Wt[(size_t)n * K + k] = __float2bfloat16(w[(size_t)k * M + off]);
  if (k == 0) biasp[n] = b[off];
}

// ---------------- per-wave barrier-free MFMA GEMM -> q bf16 | kv interleaved bf16 | skip f32 --
template <int K>
__global__ __launch_bounds__(64, 2) void k_gemm_pw(
    const __hip_bfloat16* __restrict__ X, const __hip_bfloat16* __restrict__ Wt,
    const float* __restrict__ biasp,
    __hip_bfloat16* __restrict__ qb, __hip_bfloat16* __restrict__ kvb,
    float* __restrict__ skipf,
    int nrows, int NCB, int NCH, int TPC, int RT) {
  __shared__ char lds[16384 + 2304];  // 2 x 8KB A dbuf + 16x144B epilogue scratch
  const int l = threadIdx.x;          // 0..63

  const int nwg = NCB * NCH;          // 2080, divisible by 8
  const int per = nwg >> 3;
  const int w = (blockIdx.x & 7) * per + (blockIdx.x >> 3);
  const int chunk = w / NCB;
  const int ct = w % NCB;
  const int bn = ct * 64;
  const int t0 = chunk * TPC;
  int t1 = t0 + TPC; if (t1 > RT) t1 = RT;
  constexpr int KT = K / 64;
  constexpr int NS = K / 32;

  const int lm = l & 15, lk = l >> 4;

  short8 bfr[4 * NS];
  {
    const __hip_bfloat16* bp = Wt + (size_t)(bn + lm) * K + lk * 8;
#pragma unroll
    for (int n = 0; n < 4; ++n)
#pragma unroll
      for (int s = 0; s < NS; ++s)
        bfr[n * NS + s] = *(const short8*)(bp + (size_t)n * 16 * K + s * 32);
  }
  float bia[4];
#pragma unroll
  for (int n = 0; n < 4; ++n) bia[n] = biasp[bn + n * 16 + lm];

  __hip_bfloat16* dst16 = nullptr; int cb16 = 0; size_t st16 = 1024;
  if (bn < 1024)      { dst16 = qb; cb16 = bn; st16 = 1024; }
  else if (bn < 3072) { dst16 = kvb; cb16 = bn - 1024; st16 = 2048; }

  const int jrow = l >> 3;
  const int cslot = (l & 7) ^ jrow;
  auto STAGE = [&](int buf, int t, int kt) {
    char* db = lds + buf * 8192;
#pragma unroll
    for (int j = 0; j < 8; ++j) {
      int r = t * 64 + j * 8 + jrow;
      if (r >= nrows) r = nrows - 1;
      gld16(X + (size_t)r * K + kt * 64 + cslot * 8, db + j * 1024 + l * 16);
    }
  };

  int buf = 0;
  STAGE(0, t0, 0);
  for (int t = t0; t < t1; ++t) {
    f32x4 acc[4][4] = {};
#pragma unroll
    for (int kt = 0; kt < KT; ++kt) {
      int nt = t, nk = kt + 1;
      if (nk == KT) { nt = (t + 1 < t1) ? t + 1 : t; nk = 0; }
      STAGE(buf ^ 1, nt, nk);
      asm volatile("s_waitcnt vmcnt(8)" ::: "memory");
      const char* db = lds + buf * 8192;
#pragma unroll
      for (int s2 = 0; s2 < 2; ++s2) {
        short8 a[4];
#pragma unroll
        for (int m = 0; m < 4; ++m) {
          int row = m * 16 + lm;
          a[m] = *(const short8*)(db + row * 128 + (((s2 * 4 + lk) ^ (lm & 7)) * 16));
        }
#pragma unroll
        for (int m = 0; m < 4; ++m)
#pragma unroll
          for (int n = 0; n < 4; ++n)
            acc[m][n] = __builtin_amdgcn_mfma_f32_16x16x32_bf16(
                a[m], bfr[n * NS + kt * 2 + s2], acc[m][n], 0, 0, 0);
      }
      buf ^= 1;
    }

    const int tbase = t * 64;
    if (dst16 != nullptr) {
      char* sc = lds + 16384;
      const int srow = l >> 2, qc = l & 3;
#pragma unroll
      for (int m = 0; m < 4; ++m) {
#pragma unroll
        for (int n = 0; n < 4; ++n)
#pragma unroll
          for (int r = 0; r < 4; ++r)
            *(__hip_bfloat16*)(sc + (lk * 4 + r) * 144 + (n * 16 + lm) * 2) =
                __float2bfloat16(acc[m][n][r] + bia[n]);
        const char* sr = sc + srow * 144 + qc * 32;
        short8 ta = *(const short8*)(sr);
        short8 tb = *(const short8*)(sr + 16);
        int grow = tbase + m * 16 + srow;
        if (grow < nrows) {
          ushort* o = (ushort*)dst16 + (size_t)grow * st16 + cb16 + qc * 16;
          *(short8*)o = ta;
          *(short8*)(o + 8) = tb;
        }
      }
    } else {
      const int cb = bn - 3072;
#pragma unroll
      for (int m = 0; m < 4; ++m)
#pragma unroll
        for (int n = 0; n < 4; ++n)
#pragma unroll
          for (int r = 0; r < 4; ++r) {
            int row = tbase + m * 16 + lk * 4 + r;
            if (row < nrows) skipf[(size_t)row * HIDC + cb + n * 16 + lm] = acc[m][n][r] + bia[n];
          }
    }
  }
  asm volatile("s_waitcnt vmcnt(0)" ::: "memory");
}

// ---------------- fused attention: ONE WAVE PER NODE, no LDS, no syncthreads ----------
// lane = h*16 + j: head h in [0,4), j in [0,16) owns dims [j*16, j*16+16).
// q bf16 [n][1024]; kv interleaved bf16 [n][2048]; skip f32; sse[i] = src[eid[i]].
__global__ __launch_bounds__(256) void k_attn(
    const __hip_bfloat16* __restrict__ qb, const __hip_bfloat16* __restrict__ kvb,
    const int* __restrict__ offs, const int* __restrict__ sse,
    const float* __restrict__ skipf,
    __hip_bfloat16* __restrict__ outb, float* __restrict__ outf) {
  int n = blockIdx.x * 4 + (threadIdx.x >> 6);
  if (n >= NN) return;
  int lane = threadIdx.x & 63;
  int h = lane >> 4, j = lane & 15;
  int s0 = offs[n];
  int deg = offs[n + 1] - s0;

  if (deg == 0) {  // out = skip
    if (h == 0) {
      const float* sp = skipf + (size_t)n * HIDC + j * 16;
      float v[16];
#pragma unroll
      for (int d = 0; d < 16; ++d) v[d] = sp[d];
      if (outf != nullptr) {
        float* op = outf + (size_t)n * HIDC + j * 16;
#pragma unroll
        for (int d = 0; d < 4; ++d) ((float4*)op)[d] = ((const float4*)v)[d];
      }
      if (outb != nullptr) {
        short8 o0, o1;
#pragma unroll
        for (int d = 0; d < 8; ++d) {
          o0[d] = (short)__bfloat16_as_ushort(__float2bfloat16(v[d]));
          o1[d] = (short)__bfloat16_as_ushort(__float2bfloat16(v[8 + d]));
        }
        ushort* ob = (ushort*)outb + (size_t)n * HIDC + j * 16;
        *(short8*)ob = o0;
        *(short8*)(ob + 8) = o1;
      }
    }
    return;
  }

  // Q fragment: 16 dims per lane
  float q[16];
  {
    const ushort* qr = (const ushort*)qb + (size_t)n * 1024 + h * 256 + j * 16;
    short8 q0 = *(const short8*)(qr);
    short8 q1 = *(const short8*)(qr + 8);
#pragma unroll
    for (int d = 0; d < 8; ++d) { q[d] = bf2f((unsigned short)q0[d]); q[8 + d] = bf2f((unsigned short)q1[d]); }
  }

  float acc[16];
#pragma unroll
  for (int d = 0; d < 16; ++d) acc[d] = 0.f;
  float denom = 0.f;

  const int* se = sse + s0;
  const ushort* kvbase = (const ushort*)kvb;
  const int hoff = h * 256 + j * 16;

#define LOADE(E, K0, K1, V0, V1)                                        \
  {                                                                     \
    int e_ = (E);                                                       \
    int s_ = se[(e_ < deg) ? e_ : 0];                                   \
    const ushort* r_ = kvbase + (size_t)s_ * 2048 + hoff;               \
    K0 = *(const short8*)(r_);        K1 = *(const short8*)(r_ + 8);    \
    V0 = *(const short8*)(r_ + 1024); V1 = *(const short8*)(r_ + 1032); \
  }

#define COMPE(E, K0, K1, V0, V1)                                        \
  {                                                                     \
    float p_ = 0.f;                                                     \
    _Pragma("unroll") for (int d = 0; d < 8; ++d) {                     \
      p_ = fmaf(q[d], bf2f((unsigned short)K0[d]), p_);                 \
      p_ = fmaf(q[8 + d], bf2f((unsigned short)K1[d]), p_);             \
    }                                                                   \
    p_ += __shfl_xor(p_, 1);                                            \
    p_ += __shfl_xor(p_, 2);                                            \
    p_ += __shfl_xor(p_, 4);                                            \
    p_ += __shfl_xor(p_, 8);                                            \
    float w_ = ((E) < deg) ? __expf(p_ * 0.0625f) : 0.f;                \
    denom += w_;                                                        \
    _Pragma("unroll") for (int d = 0; d < 8; ++d) {                     \
      acc[d] = fmaf(w_, bf2f((unsigned short)V0[d]), acc[d]);           \
      acc[8 + d] = fmaf(w_, bf2f((unsigned short)V1[d]), acc[8 + d]);   \
    }                                                                   \
  }

  short8 ak0, ak1, av0, av1, bk0, bk1, bv0, bv1;
  LOADE(0, ak0, ak1, av0, av1);
  for (int e = 0; e < deg; e += 2) {
    LOADE(e + 1, bk0, bk1, bv0, bv1);
    COMPE(e, ak0, ak1, av0, av1);
    LOADE(e + 2, ak0, ak1, av0, av1);
    COMPE(e + 1, bk0, bk1, bv0, bv1);
  }
#undef LOADE
#undef COMPE

  // per-head normalize, then mean over heads via cross-group shuffles
  float dinv = 1.f / (denom + 1e-16f);
  float val[16];
#pragma unroll
  for (int d = 0; d < 16; ++d) {
    float v = acc[d] * dinv;
    v += __shfl_xor(v, 16);
    v += __shfl_xor(v, 32);
    val[d] = v * 0.25f;
  }
  if (h == 0) {
    const float* sp = skipf + (size_t)n * HIDC + j * 16;
#pragma unroll
    for (int d = 0; d < 16; ++d) val[d] += sp[d];
    if (outf != nullptr) {
      float* op = outf + (size_t)n * HIDC + j * 16;
#pragma unroll
      for (int d = 0; d < 4; ++d) ((float4*)op)[d] = ((const float4*)val)[d];
    }
    if (outb != nullptr) {
      short8 o0, o1;
#pragma unroll
      for (int d = 0; d < 8; ++d) {
        o0[d] = (short)__bfloat16_as_ushort(__float2bfloat16(val[d]));
        o1[d] = (short)__bfloat16_as_ushort(__float2bfloat16(val[8 + d]));
      }
      ushort* ob = (ushort*)outb + (size_t)n * HIDC + j * 16;
      *(short8*)ob = o0;
      *(short8*)(ob + 8) = o1;
    }
  }
}

// ---------------- batch norm stats: deterministic two-stage ----------------
__global__ void k_bnstats(const float* __restrict__ x, float* __restrict__ psum,
                          float* __restrict__ psumsq) {
  int t = threadIdx.x, b = blockIdx.x;
  float s = 0.f, s2 = 0.f;
  for (int r = b; r < NN; r += 256) {
    float vv = x[(size_t)r * HIDC + t];
    s += vv; s2 += vv * vv;
  }
  psum[b * HIDC + t] = s;
  psumsq[b * HIDC + t] = s2;
}

__global__ void k_bnred(const float* __restrict__ psum, const float* __restrict__ psumsq,
                        float* __restrict__ sums, float* __restrict__ sumsq) {
  int t = threadIdx.x;
  float s = 0.f, s2 = 0.f;
  for (int b = 0; b < 256; ++b) { s += psum[b * HIDC + t]; s2 += psumsq[b * HIDC + t]; }
  sums[t] = s;
  sumsq[t] = s2;
}

// ---------------- BN apply (stats inline) + linear head + softmax + rsu row ------
__global__ __launch_bounds__(256) void k_final(
    const float* __restrict__ x, const float* __restrict__ sums, const float* __restrict__ sumsq,
    const float* __restrict__ gamma, const float* __restrict__ beta,
    const float* __restrict__ lw, const float* __restrict__ lb,
    float* __restrict__ out, int n_) {
  int sub = threadIdx.x >> 6, lane = threadIdx.x & 63;
  int n = blockIdx.x * 4 + sub;
  if (n >= n_) return;
  int c = lane * 4;
  float4 sm  = *(const float4*)(sums + c);
  float4 sq  = *(const float4*)(sumsq + c);
  const float inv_n = 1.f / (float)n_;
  float mu0 = sm.x * inv_n, mu1 = sm.y * inv_n, mu2 = sm.z * inv_n, mu3 = sm.w * inv_n;
  float r0 = 1.f / sqrtf(fmaxf(sq.x * inv_n - mu0 * mu0, 0.f) + 1e-5f);
  float r1 = 1.f / sqrtf(fmaxf(sq.y * inv_n - mu1 * mu1, 0.f) + 1e-5f);
  float r2 = 1.f / sqrtf(fmaxf(sq.z * inv_n - mu2 * mu2, 0.f) + 1e-5f);
  float r3 = 1.f / sqrtf(fmaxf(sq.w * inv_n - mu3 * mu3, 0.f) + 1e-5f);
  const float* xr = x + (size_t)n * HIDC;
  float4 xv = *(const float4*)(xr + c);
  float4 gv = *(const float4*)(gamma + c);
  float4 bv = *(const float4*)(beta + c);
  float y0 = gv.x * (xv.x - mu0) * r0 + bv.x;
  float y1 = gv.y * (xv.y - mu1) * r1 + bv.y;
  float y2 = gv.z * (xv.z - mu2) * r2 + bv.z;
  float y3 = gv.w * (xv.w - mu3) * r3 + bv.w;
  float4 wa = *(const float4*)(lw + (size_t)c * 2);
  float4 wb = *(const float4*)(lw + (size_t)c * 2 + 4);
  float p0 = y0 * wa.x + y1 * wa.z + y2 * wb.x + y3 * wb.z;
  float p1 = y0 * wa.y + y1 * wa.w + y2 * wb.y + y3 * wb.w;
#pragma unroll
  for (int off = 32; off > 0; off >>= 1) {
    p0 += __shfl_xor(p0, off);
    p1 += __shfl_xor(p1, off);
  }
  if (n == 0) *(float4*)(out + (size_t)NN * 2 + c) = make_float4(y0, y1, y2, y3);
  if (lane == 0) {
    float l0 = fmaxf(p0 + lb[0], 0.f);
    float l1 = fmaxf(p1 + lb[1], 0.f);
    float m = fmaxf(l0, l1);
    float e0 = expf(l0 - m), e1 = expf(l1 - m);
    float inv = 1.f / (e0 + e1);
    out[(size_t)n * 2 + 0] = e0 * inv;
    out[(size_t)n * 2 + 1] = e1 * inv;
  }
}

// ---------------- launch ----------------
extern "C" void kernel_launch(void* const* d_in, const int* in_sizes, int n_in,
                              void* d_out, int out_size, void* d_ws, size_t ws_size,
                              hipStream_t stream) {
  const float* x0  = (const float*)d_in[0];
  const int*   ei  = (const int*)d_in[1];
  const float* wq1 = (const float*)d_in[2];  const float* bq1 = (const float*)d_in[3];
  const float* wk1 = (const float*)d_in[4];  const float* bk1 = (const float*)d_in[5];
  const float* wv1 = (const float*)d_in[6];  const float* bv1 = (const float*)d_in[7];
  const float* ws1 = (const float*)d_in[8];  const float* bs1 = (const float*)d_in[9];
  const float* wq2 = (const float*)d_in[10]; const float* bq2 = (const float*)d_in[11];
  const float* wk2 = (const float*)d_in[12]; const float* bk2 = (const float*)d_in[13];
  const float* wv2 = (const float*)d_in[14]; const float* bv2 = (const float*)d_in[15];
  const float* ws2 = (const float*)d_in[16]; const float* bs2 = (const float*)d_in[17];
  const float* gam = (const float*)d_in[18]; const float* bet = (const float*)d_in[19];
  const float* lw  = (const float*)d_in[20]; const float* lb  = (const float*)d_in[21];
  const int* srcv = ei;
  const int* dstv = ei + NE;

  char* p = (char*)d_ws;
  auto take = [&](size_t bytes) {
    char* r = p;
    p += (bytes + 255) & ~(size_t)255;
    return r;
  };
  __hip_bfloat16* qbuf = (__hip_bfloat16*)take((size_t)NN * 1024 * 2);
  __hip_bfloat16* kvbuf = (__hip_bfloat16*)take((size_t)NN * 2048 * 2);
  float* skipf = (float*)take((size_t)NN * HIDC * 4);
  __hip_bfloat16* x0b = (__hip_bfloat16*)take((size_t)NN * FIN * 2);
  __hip_bfloat16* x2b = (__hip_bfloat16*)take((size_t)NN * HIDC * 2);
  __hip_bfloat16* Wt  = (__hip_bfloat16*)take((size_t)NOUT * HIDC * 2);
  float* x3    = (float*)take((size_t)NN * HIDC * 4);
  float* biasp = (float*)take((size_t)NOUT * 4);
  float* psum  = (float*)take(256 * HIDC * 4);
  float* psumsq= (float*)take(256 * HIDC * 4);
  float* bnbuf = (float*)take(2 * HIDC * 4);
  int* deg    = (int*)take((size_t)NN * 4);
  int* offs   = (int*)take((size_t)(NN + 1) * 4);
  int* cursor = (int*)take((size_t)NN * 4);
  int* eidb   = (int*)take((size_t)NE * 4);
  int* sse    = (int*)take((size_t)NE * 4);
  if ((size_t)(p - (char*)d_ws) > ws_size) return;

  float* sums  = bnbuf;
  float* sumsq = bnbuf + HIDC;

  hipMemsetAsync(deg, 0, (size_t)NN * 4, stream);
  k_prep<<<(NN * FIN + 255) / 256, 256, 0, stream>>>(x0, x0b, dstv, deg);
  k_scan<<<1, 1024, 0, stream>>>(deg, offs, cursor, NN);
  k_scatter<<<(NE + 255) / 256, 256, 0, stream>>>(dstv, cursor, eidb, NE);
  k_sortsse<<<(NN + 255) / 256, 256, 0, stream>>>(offs, eidb, srcv, sse, NN);

  const int RT  = (NN + 63) / 64;   // 313 row tiles (64 rows each)
  const int NCB = NOUT / 64;        // 52 col tiles (64 cols each)
  const int NCH = 40;               // row chunks
  const int TPC = (RT + NCH - 1) / NCH;  // 8 tiles per chunk
  const int GRID = NCB * NCH;       // 2080 single-wave blocks
  const int AG = (NN + 3) / 4;      // attn: 4 nodes (waves) per block
  // ---- layer 1 ----
  k_pack<FIN><<<dim3(NOUT / 128, FIN), 128, 0, stream>>>(wq1, bq1, wk1, bk1, wv1, bv1, ws1, bs1, Wt, biasp);
  k_gemm_pw<FIN><<<GRID, 64, 0, stream>>>(x0b, Wt, biasp, qbuf, kvbuf, skipf, NN, NCB, NCH, TPC, RT);
  k_attn<<<AG, 256, 0, stream>>>(qbuf, kvbuf, offs, sse, skipf, x2b, nullptr);
  // ---- layer 2 ----
  k_pack<HIDC><<<dim3(NOUT / 128, HIDC), 128, 0, stream>>>(wq2, bq2, wk2, bk2, wv2, bv2, ws2, bs2, Wt, biasp);
  k_gemm_pw<HIDC><<<GRID, 64, 0, stream>>>(x2b, Wt, biasp, qbuf, kvbuf, skipf, NN, NCB, NCH, TPC, RT);
  k_attn<<<AG, 256, 0, stream>>>(qbuf, kvbuf, offs, sse, skipf, nullptr, x3);
  // ---- BN + head ----
  k_bnstats<<<256, 256, 0, stream>>>(x3, psum, psumsq);
  k_bnred<<<1, 256, 0, stream>>>(psum, psumsq, sums, sumsq);
  k_final<<<(NN + 3) / 4, 256, 0, stream>>>(x3, sums, sumsq, gam, bet, lw, lb, (float*)d_out, NN);
}

// Round 12
// 374.301 us; speedup vs baseline: 1.2897x; 1.2897x over previous
//
#include <hip/hip_runtime.h>
#include <hip/hip_bf16.h>
#include <math.h>

#define DI __device__ __forceinline__

constexpr int NN   = 20000;
constexpr int NE   = 160000;
constexpr int FIN  = 64;
constexpr int HIDC = 256;

typedef __attribute__((ext_vector_type(8))) short short8;
typedef __attribute__((ext_vector_type(4))) float f32x4;

DI float bf2f(unsigned short u) { return __uint_as_float(((unsigned)u) << 16); }

DI void gld16(const void* g, void* l) {
  __builtin_amdgcn_global_load_lds((const __attribute__((address_space(1))) unsigned*)g,
                                   (__attribute__((address_space(3))) unsigned*)l, 16, 0, 0);
}

// ---------------- merged input cast + degree count ----------------
__global__ void k_prep(const float* __restrict__ x, __hip_bfloat16* __restrict__ xb,
                       const int* __restrict__ dst, int* __restrict__ deg) {
  int gid = blockIdx.x * 256 + threadIdx.x;
  if (gid < NN * FIN) xb[gid] = __float2bfloat16(x[gid]);
  if (gid < NE) atomicAdd(&deg[dst[gid]], 1);
}

__global__ void k_scan(const int* __restrict__ deg, int* __restrict__ offs,
                       int* __restrict__ cursor, int n_) {
  __shared__ int part[1024];
  int tid = threadIdx.x;
  const int CH = (n_ + 1023) >> 10;
  int base = tid * CH;
  int s = 0;
  for (int i = 0; i < CH; ++i) { int idx = base + i; if (idx < n_) s += deg[idx]; }
  part[tid] = s;
  __syncthreads();
  for (int off = 1; off < 1024; off <<= 1) {
    int v = (tid >= off) ? part[tid - off] : 0;
    __syncthreads();
    part[tid] += v;
    __syncthreads();
  }
  int run = (tid == 0) ? 0 : part[tid - 1];
  for (int i = 0; i < CH; ++i) {
    int idx = base + i;
    if (idx < n_) { offs[idx] = run; cursor[idx] = run; run += deg[idx]; }
  }
  if (tid == 1023) offs[n_] = run;
}

__global__ void k_scatter(const int* __restrict__ dst, int* __restrict__ cursor,
                          int* __restrict__ eid, int e_) {
  int e = blockIdx.x * blockDim.x + threadIdx.x;
  if (e < e_) {
    int p = atomicAdd(&cursor[dst[e]], 1);
    eid[p] = e;
  }
}

// ------ deterministic order: insertion-sort each node's edges, then materialize sse ------
__global__ void k_sortsse(const int* __restrict__ offs, int* __restrict__ eid,
                          const int* __restrict__ src, int* __restrict__ sse, int n_) {
  int n = blockIdx.x * 256 + threadIdx.x;
  if (n >= n_) return;
  int s0 = offs[n], s1 = offs[n + 1];
  for (int i = s0 + 1; i < s1; ++i) {
    int v = eid[i];
    int j = i - 1;
    while (j >= s0 && eid[j] > v) { eid[j + 1] = eid[j]; --j; }
    eid[j + 1] = v;
  }
  for (int i = s0; i < s1; ++i) sse[i] = src[eid[i]];
}

// ---------------- weight transposes: WqT/WkT [1024 x IN] ----------------
__global__ void k_tr(const float* __restrict__ wq, const float* __restrict__ wk,
                     float* __restrict__ WqT, float* __restrict__ WkT, int IN_) {
  int gid = blockIdx.x * 256 + threadIdx.x;
  if (gid >= 1024 * IN_) return;
  int k = gid % IN_, j = gid / IN_;
  WqT[gid] = wq[(size_t)k * 1024 + j];
  WkT[gid] = wk[(size_t)k * 1024 + j];
}

// -------- GEMM1 weight build: cols = [4*IN y (bilinear) | 256 skip | 4 C | 4 D | pad] -----
template <int IN>
__global__ void k_mfill(const float* __restrict__ WqT, const float* __restrict__ WkT,
                        const float* __restrict__ bq, const float* __restrict__ bk,
                        const float* __restrict__ ws, const float* __restrict__ bs,
                        __hip_bfloat16* __restrict__ Wt, float* __restrict__ biasp) {
  constexpr int YW = 4 * IN;
  constexpr int CPB = 256 / IN;
  int k = threadIdx.x % IN;
  int sub = threadIdx.x / IN;
  int c = blockIdx.x * CPB + sub;
  float val = 0.f, bval = 0.f;
  if (c < YW) {
    int h = c / IN, i = c % IN;
    const float* wqp = WqT + (size_t)(h * 256) * IN + k;
    const float* wkp = WkT + (size_t)(h * 256) * IN + i;
    float s = 0.f;
#pragma unroll 4
    for (int j = 0; j < 256; ++j) s = fmaf(wqp[(size_t)j * IN], wkp[(size_t)j * IN], s);
    val = s;
  } else if (c < YW + 256) {
    int sc = c - YW;
    val = ws[(size_t)k * 256 + sc];
    bval = bs[sc];
  } else if (c < YW + 260) {
    int h = c - (YW + 256);
    const float* wqp = WqT + (size_t)(h * 256) * IN + k;
    const float* bkp = bk + h * 256;
    float s = 0.f;
#pragma unroll 4
    for (int j = 0; j < 256; ++j) s = fmaf(wqp[(size_t)j * IN], bkp[j], s);
    val = s;
    if (k == 0) {
      float bb = 0.f;
      for (int j = 0; j < 256; ++j) bb = fmaf(bq[h * 256 + j], bk[h * 256 + j], bb);
      bval = bb;
    }
  } else if (c < YW + 264) {
    int h = c - (YW + 260);
    const float* wkp = WkT + (size_t)(h * 256) * IN + k;
    const float* bqp = bq + h * 256;
    float s = 0.f;
#pragma unroll 4
    for (int j = 0; j < 256; ++j) s = fmaf(wkp[(size_t)j * IN], bqp[j], s);
    val = s;
  }
  Wt[(size_t)c * IN + k] = __float2bfloat16(val);
  if (k == 0) biasp[c] = bval;
}

// ---------------- GEMM2 weight pack: Wt2[col][k=h*IN+d] = wv[d][h*256+col]/4 ----------------
template <int IN>
__global__ void k_pack2(const float* __restrict__ wv, const float* __restrict__ bv,
                        __hip_bfloat16* __restrict__ Wt2, float* __restrict__ bias2) {
  constexpr int K2 = 4 * IN;
  int gid = blockIdx.x * 256 + threadIdx.x;
  int col = gid / K2, k = gid % K2;
  int h = k / IN, d = k % IN;
  Wt2[gid] = __float2bfloat16(0.25f * wv[(size_t)d * 1024 + h * 256 + col]);
  if (k == 0)
    bias2[col] = 0.25f * (bv[col] + bv[256 + col] + bv[512 + col] + bv[768 + col]);
}

// ---------------- GEMM1: X[nrows x IN] @ Wt1 -> Y bf16 | skip f32 | CD f32 ----------------
template <int IN>
__global__ __launch_bounds__(64, 2) void k_gemm1(
    const __hip_bfloat16* __restrict__ X, const __hip_bfloat16* __restrict__ Wt,
    const float* __restrict__ biasp,
    __hip_bfloat16* __restrict__ Ybuf, float* __restrict__ skipf,
    float* __restrict__ CDbuf, int nrows, int NCB, int NCH, int TPC, int RT) {
  __shared__ char lds[16384 + 2304];
  const int l = threadIdx.x;
  constexpr int K = IN;
  constexpr int YW = 4 * IN;
  const int nwg = NCB * NCH;
  const int per = nwg >> 3;
  const int w = (blockIdx.x & 7) * per + (blockIdx.x >> 3);
  const int chunk = w / NCB;
  const int ct = w % NCB;
  const int bn = ct * 64;
  const int t0 = chunk * TPC;
  int t1 = t0 + TPC; if (t1 > RT) t1 = RT;
  constexpr int KT = K / 64;
  constexpr int NS = K / 32;

  const int lm = l & 15, lk = l >> 4;

  short8 bfr[4 * NS];
  {
    const __hip_bfloat16* bp = Wt + (size_t)(bn + lm) * K + lk * 8;
#pragma unroll
    for (int n = 0; n < 4; ++n)
#pragma unroll
      for (int s = 0; s < NS; ++s)
        bfr[n * NS + s] = *(const short8*)(bp + (size_t)n * 16 * K + s * 32);
  }
  float bia[4];
#pragma unroll
  for (int n = 0; n < 4; ++n) bia[n] = biasp[bn + n * 16 + lm];

  const int mode = (bn < YW) ? 0 : ((bn < YW + 256) ? 1 : 2);

  const int jrow = l >> 3;
  const int cslot = (l & 7) ^ jrow;
  auto STAGE = [&](int buf, int t, int kt) {
    char* db = lds + buf * 8192;
#pragma unroll
    for (int j = 0; j < 8; ++j) {
      int r = t * 64 + j * 8 + jrow;
      if (r >= nrows) r = nrows - 1;
      gld16(X + (size_t)r * K + kt * 64 + cslot * 8, db + j * 1024 + l * 16);
    }
  };

  int buf = 0;
  STAGE(0, t0, 0);
  for (int t = t0; t < t1; ++t) {
    f32x4 acc[4][4] = {};
#pragma unroll
    for (int kt = 0; kt < KT; ++kt) {
      int nt = t, nk = kt + 1;
      if (nk == KT) { nt = (t + 1 < t1) ? t + 1 : t; nk = 0; }
      STAGE(buf ^ 1, nt, nk);
      asm volatile("s_waitcnt vmcnt(8)" ::: "memory");
      const char* db = lds + buf * 8192;
#pragma unroll
      for (int s2 = 0; s2 < 2; ++s2) {
        short8 a[4];
#pragma unroll
        for (int m = 0; m < 4; ++m) {
          int row = m * 16 + lm;
          a[m] = *(const short8*)(db + row * 128 + (((s2 * 4 + lk) ^ (lm & 7)) * 16));
        }
#pragma unroll
        for (int m = 0; m < 4; ++m)
#pragma unroll
          for (int n = 0; n < 4; ++n)
            acc[m][n] = __builtin_amdgcn_mfma_f32_16x16x32_bf16(
                a[m], bfr[n * NS + kt * 2 + s2], acc[m][n], 0, 0, 0);
      }
      buf ^= 1;
    }

    const int tbase = t * 64;
    if (mode == 0) {
      // bf16 Y output via per-wave LDS transpose
      char* sc = lds + 16384;
      const int srow = l >> 2, qc = l & 3;
#pragma unroll
      for (int m = 0; m < 4; ++m) {
#pragma unroll
        for (int n = 0; n < 4; ++n)
#pragma unroll
          for (int r = 0; r < 4; ++r)
            *(__hip_bfloat16*)(sc + (lk * 4 + r) * 144 + (n * 16 + lm) * 2) =
                __float2bfloat16(acc[m][n][r] + bia[n]);
        const char* sr = sc + srow * 144 + qc * 32;
        short8 ta = *(const short8*)(sr);
        short8 tb = *(const short8*)(sr + 16);
        int grow = tbase + m * 16 + srow;
        if (grow < nrows) {
          ushort* o = (ushort*)Ybuf + (size_t)grow * YW + bn + qc * 16;
          *(short8*)o = ta;
          *(short8*)(o + 8) = tb;
        }
      }
    } else if (mode == 1) {
      const int cb = bn - YW;
#pragma unroll
      for (int m = 0; m < 4; ++m)
#pragma unroll
        for (int n = 0; n < 4; ++n)
#pragma unroll
          for (int r = 0; r < 4; ++r) {
            int row = tbase + m * 16 + lk * 4 + r;
            if (row < nrows) skipf[(size_t)row * HIDC + cb + n * 16 + lm] = acc[m][n][r] + bia[n];
          }
    } else {
      // CD block: only first 8 local cols are real
#pragma unroll
      for (int m = 0; m < 4; ++m)
#pragma unroll
        for (int n = 0; n < 4; ++n) {
          int cl = n * 16 + lm;
          if (cl < 8) {
#pragma unroll
            for (int r = 0; r < 4; ++r) {
              int row = tbase + m * 16 + lk * 4 + r;
              if (row < nrows) CDbuf[(size_t)row * 8 + cl] = acc[m][n][r] + bia[n];
            }
          }
        }
    }
  }
  asm volatile("s_waitcnt vmcnt(0)" ::: "memory");
}

// ---------------- attention: wave-per-node, gathers only x_src (IN dims) ----------------
// lane = h*16 + j; alpha = y_d.x_s + C_d + D_s; z_h = sum(a * x_s).
template <int IN>
__global__ __launch_bounds__(256) void k_attn(
    const __hip_bfloat16* __restrict__ Ybuf, const __hip_bfloat16* __restrict__ Xs,
    const float* __restrict__ CD, const int* __restrict__ offs,
    const int* __restrict__ sse, __hip_bfloat16* __restrict__ Zbuf,
    float* __restrict__ Abuf) {
  constexpr int DPL = IN / 16;
  constexpr int YW = 4 * IN;
  int n = blockIdx.x * 4 + (threadIdx.x >> 6);
  if (n >= NN) return;
  int lane = threadIdx.x & 63;
  int h = lane >> 4, j = lane & 15;
  int s0 = offs[n];
  int deg = offs[n + 1] - s0;
  ushort* zr = (ushort*)Zbuf + (size_t)n * YW + h * IN + j * DPL;
  if (deg == 0) {
#pragma unroll
    for (int d = 0; d < DPL; ++d) zr[d] = 0;
    if (lane == 0) Abuf[n] = 0.f;
    return;
  }

  float y[DPL];
  {
    const ushort* yr = (const ushort*)Ybuf + (size_t)n * YW + h * IN + j * DPL;
    if constexpr (IN == 256) {
      short8 y0 = *(const short8*)yr;
      short8 y1 = *(const short8*)(yr + 8);
#pragma unroll
      for (int d = 0; d < 8; ++d) {
        y[d] = bf2f((unsigned short)y0[d]);
        y[8 + d] = bf2f((unsigned short)y1[d]);
      }
    } else {
      short4 yv = *(const short4*)yr;
      y[0] = bf2f((unsigned short)yv.x);
      y[1] = bf2f((unsigned short)yv.y);
      y[2] = bf2f((unsigned short)yv.z);
      y[3] = bf2f((unsigned short)yv.w);
    }
  }
  float C = CD[(size_t)n * 8 + h];
  float acc[DPL] = {};
  float denom = 0.f;
  const int* se = sse + s0;
  const ushort* xb = (const ushort*)Xs;

#define LOADE(P, E)                                                     \
  {                                                                     \
    int e_ = (E);                                                       \
    int s_ = se[(e_ < deg) ? e_ : 0];                                   \
    const ushort* xp_ = xb + (size_t)s_ * IN + j * DPL;                 \
    if constexpr (IN == 256) {                                          \
      P##0 = *(const short8*)xp_;                                       \
      P##1 = *(const short8*)(xp_ + 8);                                 \
    } else {                                                            \
      P##s = *(const short4*)xp_;                                       \
    }                                                                   \
    P##D = CD[(size_t)s_ * 8 + 4 + h];                                  \
  }

#define COMPE(P, E)                                                     \
  {                                                                     \
    float xf[DPL];                                                      \
    if constexpr (IN == 256) {                                          \
      _Pragma("unroll") for (int d = 0; d < 8; ++d) {                   \
        xf[d] = bf2f((unsigned short)P##0[d]);                          \
        xf[8 + d] = bf2f((unsigned short)P##1[d]);                      \
      }                                                                 \
    } else {                                                            \
      xf[0] = bf2f((unsigned short)P##s.x);                             \
      xf[1] = bf2f((unsigned short)P##s.y);                             \
      xf[2] = bf2f((unsigned short)P##s.z);                             \
      xf[3] = bf2f((unsigned short)P##s.w);                             \
    }                                                                   \
    float p_ = 0.f;                                                     \
    _Pragma("unroll") for (int d = 0; d < DPL; ++d) p_ = fmaf(y[d], xf[d], p_); \
    p_ += __shfl_xor(p_, 1);                                            \
    p_ += __shfl_xor(p_, 2);                                            \
    p_ += __shfl_xor(p_, 4);                                            \
    p_ += __shfl_xor(p_, 8);                                            \
    float w_ = ((E) < deg) ? __expf((p_ + C + P##D) * 0.0625f) : 0.f;   \
    denom += w_;                                                        \
    _Pragma("unroll") for (int d = 0; d < DPL; ++d) acc[d] = fmaf(w_, xf[d], acc[d]); \
  }

  short8 A0, A1, B0, B1;
  short4 As, Bs;
  float AD, BD;
  (void)As; (void)Bs; (void)A0; (void)A1; (void)B0; (void)B1;
  LOADE(A, 0);
  for (int e = 0; e < deg; e += 2) {
    LOADE(B, e + 1);
    COMPE(A, e);
    LOADE(A, e + 2);
    COMPE(B, e + 1);
  }
#undef LOADE
#undef COMPE

  float dinv = 1.f / (denom + 1e-16f);
  if constexpr (IN == 256) {
    short8 o0, o1;
#pragma unroll
    for (int d = 0; d < 8; ++d) {
      o0[d] = (short)__bfloat16_as_ushort(__float2bfloat16(acc[d] * dinv));
      o1[d] = (short)__bfloat16_as_ushort(__float2bfloat16(acc[8 + d] * dinv));
    }
    *(short8*)zr = o0;
    *(short8*)(zr + 8) = o1;
  } else {
    short4 o;
    o.x = (short)__bfloat16_as_ushort(__float2bfloat16(acc[0] * dinv));
    o.y = (short)__bfloat16_as_ushort(__float2bfloat16(acc[1] * dinv));
    o.z = (short)__bfloat16_as_ushort(__float2bfloat16(acc[2] * dinv));
    o.w = (short)__bfloat16_as_ushort(__float2bfloat16(acc[3] * dinv));
    *(short4*)zr = o;
  }
  if (lane == 0) Abuf[n] = 1.f;
}

// ---------------- GEMM2: Z[nrows x K2] @ Wt2[256 x K2] + A*bias2 + skip -> out ----------------
// Per-wave block, 128-col strip, B streamed from global per chunk (issued before A-prefetch).
template <int K2, bool F32OUT>
__global__ __launch_bounds__(64, 2) void k_gemm2(
    const __hip_bfloat16* __restrict__ Z, const __hip_bfloat16* __restrict__ Wt2,
    const float* __restrict__ bias2, const float* __restrict__ Abuf,
    const float* __restrict__ skipf, void* __restrict__ outp, int nrows) {
  __shared__ char lds[16384];
  const int l = threadIdx.x;
  const int tile = blockIdx.x >> 1;
  const int bn = (blockIdx.x & 1) * 128;
  constexpr int KT = K2 / 64;
  const int lm = l & 15, lk = l >> 4;
  const int jrow = l >> 3, cslot = (l & 7) ^ jrow;

  float bia[8];
#pragma unroll
  for (int n = 0; n < 8; ++n) bia[n] = bias2[bn + n * 16 + lm];

  auto STAGE = [&](int buf, int ch) {
    char* db = lds + buf * 8192;
#pragma unroll
    for (int jj = 0; jj < 8; ++jj) {
      int r = tile * 64 + jj * 8 + jrow;
      if (r >= nrows) r = nrows - 1;
      gld16(Z + (size_t)r * K2 + ch * 64 + cslot * 8, db + jj * 1024 + l * 16);
    }
  };

  f32x4 acc[4][8] = {};
  int buf = 0;
  STAGE(0, 0);
  for (int ch = 0; ch < KT; ++ch) {
    short8 bfr[8][2];
    const __hip_bfloat16* bp = Wt2 + (size_t)(bn + lm) * K2 + ch * 64 + lk * 8;
#pragma unroll
    for (int n = 0; n < 8; ++n)
#pragma unroll
      for (int s2 = 0; s2 < 2; ++s2)
        bfr[n][s2] = *(const short8*)(bp + (size_t)n * 16 * K2 + s2 * 32);
    STAGE(buf ^ 1, (ch + 1 < KT) ? ch + 1 : ch);
    asm volatile("s_waitcnt vmcnt(8)" ::: "memory");
    const char* db = lds + buf * 8192;
#pragma unroll
    for (int s2 = 0; s2 < 2; ++s2) {
      short8 a[4];
#pragma unroll
      for (int m = 0; m < 4; ++m) {
        int row = m * 16 + lm;
        a[m] = *(const short8*)(db + row * 128 + (((s2 * 4 + lk) ^ (lm & 7)) * 16));
      }
#pragma unroll
      for (int m = 0; m < 4; ++m)
#pragma unroll
        for (int n = 0; n < 8; ++n)
          acc[m][n] = __builtin_amdgcn_mfma_f32_16x16x32_bf16(a[m], bfr[n][s2], acc[m][n], 0, 0, 0);
    }
    buf ^= 1;
  }

  const int tbase = tile * 64;
#pragma unroll
  for (int m = 0; m < 4; ++m)
#pragma unroll
    for (int r = 0; r < 4; ++r) {
      int row = tbase + m * 16 + lk * 4 + r;
      if (row >= nrows) continue;
      float af = Abuf[row];
#pragma unroll
      for (int n = 0; n < 8; ++n) {
        int col = bn + n * 16 + lm;
        float v = acc[m][n][r] + af * bia[n] + skipf[(size_t)row * HIDC + col];
        if constexpr (F32OUT)
          ((float*)outp)[(size_t)row * HIDC + col] = v;
        else
          ((ushort*)outp)[(size_t)row * HIDC + col] = __bfloat16_as_ushort(__float2bfloat16(v));
      }
    }
  asm volatile("s_waitcnt vmcnt(0)" ::: "memory");
}

// ---------------- batch norm stats: deterministic two-stage ----------------
__global__ void k_bnstats(const float* __restrict__ x, float* __restrict__ psum,
                          float* __restrict__ psumsq) {
  int t = threadIdx.x, b = blockIdx.x;
  float s = 0.f, s2 = 0.f;
  for (int r = b; r < NN; r += 256) {
    float vv = x[(size_t)r * HIDC + t];
    s += vv; s2 += vv * vv;
  }
  psum[b * HIDC + t] = s;
  psumsq[b * HIDC + t] = s2;
}

__global__ void k_bnred(const float* __restrict__ psum, const float* __restrict__ psumsq,
                        float* __restrict__ sums, float* __restrict__ sumsq) {
  int t = threadIdx.x;
  float s = 0.f, s2 = 0.f;
  for (int b = 0; b < 256; ++b) { s += psum[b * HIDC + t]; s2 += psumsq[b * HIDC + t]; }
  sums[t] = s;
  sumsq[t] = s2;
}

// ---------------- BN apply + linear head + softmax + rsu row ----------------
__global__ __launch_bounds__(256) void k_final(
    const float* __restrict__ x, const float* __restrict__ sums, const float* __restrict__ sumsq,
    const float* __restrict__ gamma, const float* __restrict__ beta,
    const float* __restrict__ lw, const float* __restrict__ lb,
    float* __restrict__ out, int n_) {
  int sub = threadIdx.x >> 6, lane = threadIdx.x & 63;
  int n = blockIdx.x * 4 + sub;
  if (n >= n_) return;
  int c = lane * 4;
  float4 sm  = *(const float4*)(sums + c);
  float4 sq  = *(const float4*)(sumsq + c);
  const float inv_n = 1.f / (float)n_;
  float mu0 = sm.x * inv_n, mu1 = sm.y * inv_n, mu2 = sm.z * inv_n, mu3 = sm.w * inv_n;
  float r0 = 1.f / sqrtf(fmaxf(sq.x * inv_n - mu0 * mu0, 0.f) + 1e-5f);
  float r1 = 1.f / sqrtf(fmaxf(sq.y * inv_n - mu1 * mu1, 0.f) + 1e-5f);
  float r2 = 1.f / sqrtf(fmaxf(sq.z * inv_n - mu2 * mu2, 0.f) + 1e-5f);
  float r3 = 1.f / sqrtf(fmaxf(sq.w * inv_n - mu3 * mu3, 0.f) + 1e-5f);
  const float* xr = x + (size_t)n * HIDC;
  float4 xv = *(const float4*)(xr + c);
  float4 gv = *(const float4*)(gamma + c);
  float4 bv = *(const float4*)(beta + c);
  float y0 = gv.x * (xv.x - mu0) * r0 + bv.x;
  float y1 = gv.y * (xv.y - mu1) * r1 + bv.y;
  float y2 = gv.z * (xv.z - mu2) * r2 + bv.z;
  float y3 = gv.w * (xv.w - mu3) * r3 + bv.w;
  float4 wa = *(const float4*)(lw + (size_t)c * 2);
  float4 wb = *(const float4*)(lw + (size_t)c * 2 + 4);
  float p0 = y0 * wa.x + y1 * wa.z + y2 * wb.x + y3 * wb.z;
  float p1 = y0 * wa.y + y1 * wa.w + y2 * wb.y + y3 * wb.w;
#pragma unroll
  for (int off = 32; off > 0; off >>= 1) {
    p0 += __shfl_xor(p0, off);
    p1 += __shfl_xor(p1, off);
  }
  if (n == 0) *(float4*)(out + (size_t)NN * 2 + c) = make_float4(y0, y1, y2, y3);
  if (lane == 0) {
    float l0 = fmaxf(p0 + lb[0], 0.f);
    float l1 = fmaxf(p1 + lb[1], 0.f);
    float m = fmaxf(l0, l1);
    float e0 = expf(l0 - m), e1 = expf(l1 - m);
    float inv = 1.f / (e0 + e1);
    out[(size_t)n * 2 + 0] = e0 * inv;
    out[(size_t)n * 2 + 1] = e1 * inv;
  }
}

// ---------------- launch ----------------
extern "C" void kernel_launch(void* const* d_in, const int* in_sizes, int n_in,
                              void* d_out, int out_size, void* d_ws, size_t ws_size,
                              hipStream_t stream) {
  const float* x0  = (const float*)d_in[0];
  const int*   ei  = (const int*)d_in[1];
  const float* wq1 = (const float*)d_in[2];  const float* bq1 = (const float*)d_in[3];
  const float* wk1 = (const float*)d_in[4];  const float* bk1 = (const float*)d_in[5];
  const float* wv1 = (const float*)d_in[6];  const float* bv1 = (const float*)d_in[7];
  const float* ws1 = (const float*)d_in[8];  const float* bs1 = (const float*)d_in[9];
  const float* wq2 = (const float*)d_in[10]; const float* bq2 = (const float*)d_in[11];
  const float* wk2 = (const float*)d_in[12]; const float* bk2 = (const float*)d_in[13];
  const float* wv2 = (const float*)d_in[14]; const float* bv2 = (const float*)d_in[15];
  const float* ws2 = (const float*)d_in[16]; const float* bs2 = (const float*)d_in[17];
  const float* gam = (const float*)d_in[18]; const float* bet = (const float*)d_in[19];
  const float* lw  = (const float*)d_in[20]; const float* lb  = (const float*)d_in[21];
  const int* srcv = ei;
  const int* dstv = ei + NE;

  char* p = (char*)d_ws;
  auto take = [&](size_t bytes) {
    char* r = p;
    p += (bytes + 255) & ~(size_t)255;
    return r;
  };
  __hip_bfloat16* Ybuf = (__hip_bfloat16*)take((size_t)NN * 1024 * 2);
  __hip_bfloat16* Zbuf = (__hip_bfloat16*)take((size_t)NN * 1024 * 2);
  float* skipf = (float*)take((size_t)NN * HIDC * 4);
  float* x3    = (float*)take((size_t)NN * HIDC * 4);
  __hip_bfloat16* x0b = (__hip_bfloat16*)take((size_t)NN * FIN * 2);
  __hip_bfloat16* x2b = (__hip_bfloat16*)take((size_t)NN * HIDC * 2);
  float* CDbuf = (float*)take((size_t)NN * 8 * 4);
  float* Abuf  = (float*)take((size_t)NN * 4);
  __hip_bfloat16* Wt1a = (__hip_bfloat16*)take((size_t)576 * 64 * 2);
  __hip_bfloat16* Wt1b = (__hip_bfloat16*)take((size_t)1344 * 256 * 2);
  float* bias1a = (float*)take(576 * 4);
  float* bias1b = (float*)take(1344 * 4);
  __hip_bfloat16* Wt2a = (__hip_bfloat16*)take((size_t)256 * 256 * 2);
  __hip_bfloat16* Wt2b = (__hip_bfloat16*)take((size_t)256 * 1024 * 2);
  float* bias2a = (float*)take(256 * 4);
  float* bias2b = (float*)take(256 * 4);
  float* WqTa = (float*)take((size_t)1024 * 64 * 4);
  float* WkTa = (float*)take((size_t)1024 * 64 * 4);
  float* WqTb = (float*)take((size_t)1024 * 256 * 4);
  float* WkTb = (float*)take((size_t)1024 * 256 * 4);
  float* psum  = (float*)take(256 * HIDC * 4);
  float* psumsq= (float*)take(256 * HIDC * 4);
  float* bnbuf = (float*)take(2 * HIDC * 4);
  int* deg    = (int*)take((size_t)NN * 4);
  int* offs   = (int*)take((size_t)(NN + 1) * 4);
  int* cursor = (int*)take((size_t)NN * 4);
  int* eidb   = (int*)take((size_t)NE * 4);
  int* sse    = (int*)take((size_t)NE * 4);
  if ((size_t)(p - (char*)d_ws) > ws_size) return;

  float* sums  = bnbuf;
  float* sumsq = bnbuf + HIDC;

  hipMemsetAsync(deg, 0, (size_t)NN * 4, stream);
  k_prep<<<(NN * FIN + 255) / 256, 256, 0, stream>>>(x0, x0b, dstv, deg);
  k_scan<<<1, 1024, 0, stream>>>(deg, offs, cursor, NN);
  k_scatter<<<(NE + 255) / 256, 256, 0, stream>>>(dstv, cursor, eidb, NE);
  k_sortsse<<<(NN + 255) / 256, 256, 0, stream>>>(offs, eidb, srcv, sse, NN);

  // ---- weight precompute (data-independent) ----
  k_tr<<<(1024 * 64 + 255) / 256, 256, 0, stream>>>(wq1, wk1, WqTa, WkTa, 64);
  k_mfill<64><<<144, 256, 0, stream>>>(WqTa, WkTa, bq1, bk1, ws1, bs1, Wt1a, bias1a);
  k_pack2<64><<<256, 256, 0, stream>>>(wv1, bv1, Wt2a, bias2a);
  k_tr<<<(1024 * 256 + 255) / 256, 256, 0, stream>>>(wq2, wk2, WqTb, WkTb, 256);
  k_mfill<256><<<1344, 256, 0, stream>>>(WqTb, WkTb, bq2, bk2, ws2, bs2, Wt1b, bias1b);
  k_pack2<256><<<1024, 256, 0, stream>>>(wv2, bv2, Wt2b, bias2b);

  const int RT  = (NN + 63) / 64;   // 313 row tiles
  const int NCH = 40;
  const int TPC = (RT + NCH - 1) / NCH;  // 8
  const int AG = (NN + 3) / 4;      // 5000
  const int G2 = RT * 2;            // 626

  // ---- layer 1 ----
  k_gemm1<64><<<9 * NCH, 64, 0, stream>>>(x0b, Wt1a, bias1a, Ybuf, skipf, CDbuf, NN, 9, NCH, TPC, RT);
  k_attn<64><<<AG, 256, 0, stream>>>(Ybuf, x0b, CDbuf, offs, sse, Zbuf, Abuf);
  k_gemm2<256, false><<<G2, 64, 0, stream>>>(Zbuf, Wt2a, bias2a, Abuf, skipf, x2b, NN);
  // ---- layer 2 ----
  k_gemm1<256><<<21 * NCH, 64, 0, stream>>>(x2b, Wt1b, bias1b, Ybuf, skipf, CDbuf, NN, 21, NCH, TPC, RT);
  k_attn<256><<<AG, 256, 0, stream>>>(Ybuf, x2b, CDbuf, offs, sse, Zbuf, Abuf);
  k_gemm2<1024, true><<<G2, 64, 0, stream>>>(Zbuf, Wt2b, bias2b, Abuf, skipf, x3, NN);
  // ---- BN + head ----
  k_bnstats<<<256, 256, 0, stream>>>(x3, psum, psumsq);
  k_bnred<<<1, 256, 0, stream>>>(psum, psumsq, sums, sumsq);
  k_final<<<(NN + 3) / 4, 256, 0, stream>>>(x3, sums, sumsq, gam, bet, lw, lb, (float*)d_out, NN);
}